// Round 1
// baseline (126.480 us; speedup 1.0000x reference)
//
#include <hip/hip_runtime.h>
#include <stdint.h>

#define GLOBAL_AS __attribute__((address_space(1)))
#define LDS_AS    __attribute__((address_space(3)))

typedef __attribute__((ext_vector_type(8))) __bf16 bf16x8;
typedef __attribute__((ext_vector_type(4))) float  f32x4;

static_assert(sizeof(bf16x8) == 16, "bf16x8 must be 16B");

constexpr int N  = 4096;   // B*P rows
constexpr int DK = 512;    // feature dim

// ---------------------------------------------------------------------------
// ws layout:
//   Xb       : bf16 [4096][512]        @ 0          (4 MiB)
//   cls      : int32[4096]             @ 4 MiB      (16 KiB)
//   partials : float4 [4096][32]       @ 4MiB+16KiB (2 MiB)  {S,P,E,W}
// ---------------------------------------------------------------------------

__global__ void k_convert(const float* __restrict__ X, __bf16* __restrict__ Xb) {
    int idx = blockIdx.x * blockDim.x + threadIdx.x;   // 262144 threads, 8 elems each
    const float4* s = (const float4*)X;
    float4 a = s[2 * idx + 0];
    float4 b = s[2 * idx + 1];
    bf16x8 o;
    o[0] = (__bf16)a.x; o[1] = (__bf16)a.y; o[2] = (__bf16)a.z; o[3] = (__bf16)a.w;
    o[4] = (__bf16)b.x; o[5] = (__bf16)b.y; o[6] = (__bf16)b.z; o[7] = (__bf16)b.w;
    *(bf16x8*)(Xb + 8 * idx) = o;
}

// targets may arrive as int64 (ref uses jnp.int64) or int32 (x64 disabled).
// int64 little-endian => odd int32 words are all zero (values in [0,128)).
// Only inspect first 1024 int32 words (safe under either allocation size).
__global__ void k_cls(const int* __restrict__ tbuf, int* __restrict__ cls) {
    __shared__ int is64;
    int t = threadIdx.x;                 // 1024 threads, 1 block
    if (t == 0) is64 = 1;
    __syncthreads();
    if (t < 512 && tbuf[2 * t + 1] != 0) is64 = 0;
    __syncthreads();
    int idx = is64 ? (2 * t) : t;        // single guarded load, no OOB speculation
    int v = tbuf[idx];
    cls[4 * t + 0] = v;
    cls[4 * t + 1] = v;
    cls[4 * t + 2] = v;
    cls[4 * t + 3] = v;
}

// Main fused kernel: 128x128 output tile per block, K=512 loop, bf16 MFMA,
// epilogue folds (S,P,E,W) row-accumulators. Grid = 32x32 = 1024 blocks.
__launch_bounds__(256, 3)
__global__ void k_main(const __bf16* __restrict__ Xb, const int* __restrict__ cls,
                       float* __restrict__ partials) {
    __shared__ __align__(16) __bf16 As[128 * 64];   // [row][k] bf16, row stride 128B
    __shared__ __align__(16) __bf16 Bs[128 * 64];   // [col][k] bf16 (B = X^T => rows of X)
    __shared__ float accS[128], accP[128], accE[128], accW[128];
    __shared__ int rowcls[128], colcls[128];

    const int tid  = threadIdx.x;
    const int lane = tid & 63;
    const int wid  = tid >> 6;
    const int rt = blockIdx.x & 31;
    const int g  = blockIdx.x >> 5;
    const int i0 = rt * 128;
    const int j0 = g * 128;

    if (tid < 128) {
        rowcls[tid] = cls[i0 + tid];
        colcls[tid] = cls[j0 + tid];
        accS[tid] = 0.f; accP[tid] = 0.f; accE[tid] = 0.f; accW[tid] = 0.f;
    }

    const int wr = wid >> 1;          // wave row (0..1) -> rows wr*64..+63
    const int wc = wid & 1;           // wave col (0..1) -> cols wc*64..+63

    f32x4 acc[4][4] = {};

    const char* xb   = (const char*)Xb;
    const int   srow = tid >> 3;          // 0..31 (staging row within 32-row slab)
    const int   skb  = (tid & 7) * 16;    // 0..112 (staging k-byte)
    char* AsB = (char*)As;
    char* BsB = (char*)Bs;
    const int ldsOff = wid * 1024;        // wave-uniform LDS base offset

    const int rA   = lane & 15;           // fragment row/col within 16
    const int kgrp = lane >> 4;           // 0..3

    for (int kt = 0; kt < DK / 64; ++kt) {
        const size_t kb0 = (size_t)kt * 128;   // k-tile byte offset within a row
        // stage A (rows i0..) and B (rows j0..) tiles: 8x global_load_lds_dwordx4
#pragma unroll
        for (int t = 0; t < 4; ++t) {
            __builtin_amdgcn_global_load_lds(
                (const GLOBAL_AS void*)(xb + (size_t)(i0 + t * 32 + srow) * 1024 + kb0 + skb),
                (LDS_AS void*)(AsB + t * 4096 + ldsOff), 16, 0, 0);
            __builtin_amdgcn_global_load_lds(
                (const GLOBAL_AS void*)(xb + (size_t)(j0 + t * 32 + srow) * 1024 + kb0 + skb),
                (LDS_AS void*)(BsB + t * 4096 + ldsOff), 16, 0, 0);
        }
        __syncthreads();   // compiler drains vmcnt before barrier => tiles ready
#pragma unroll
        for (int kk = 0; kk < 2; ++kk) {
            const int koff = kk * 64 + kgrp * 16;   // k bytes within tile row
            bf16x8 af[4], bg[4];
#pragma unroll
            for (int m = 0; m < 4; ++m)
                af[m] = *(const bf16x8*)(AsB + (wr * 64 + m * 16 + rA) * 128 + koff);
#pragma unroll
            for (int n = 0; n < 4; ++n)
                bg[n] = *(const bf16x8*)(BsB + (wc * 64 + n * 16 + rA) * 128 + koff);
#pragma unroll
            for (int m = 0; m < 4; ++m)
#pragma unroll
                for (int n = 0; n < 4; ++n)
                    acc[m][n] = __builtin_amdgcn_mfma_f32_16x16x32_bf16(af[m], bg[n],
                                                                        acc[m][n], 0, 0, 0);
        }
        __syncthreads();   // all waves done reading before next-tile overwrite
    }

    // ---- epilogue: fold acc into per-row (S, P, E, W) ----
    // C/D layout: col = lane&15, row = (lane>>4)*4 + reg  [m89-verified]
    // part(i) = i&3: rows => r (reg idx), cols => lane&3 (all tile bases %4 == 0)
    const int pj = lane & 3;
#pragma unroll
    for (int m = 0; m < 4; ++m) {
        const int rbase = wr * 64 + m * 16 + kgrp * 4;
        int ci[4];
#pragma unroll
        for (int r = 0; r < 4; ++r) ci[r] = rowcls[rbase + r];
        float sS[4] = {0.f, 0.f, 0.f, 0.f};
        float sP[4] = {0.f, 0.f, 0.f, 0.f};
        float sE[4] = {0.f, 0.f, 0.f, 0.f};
        float sW[4] = {0.f, 0.f, 0.f, 0.f};
#pragma unroll
        for (int n = 0; n < 4; ++n) {
            const int cj = colcls[wc * 64 + n * 16 + rA];
#pragma unroll
            for (int r = 0; r < 4; ++r) {
                const float p  = acc[m][n][r];
                const float ep = __expf(p);
                const bool sc = (ci[r] == cj);
                const bool sp = (r == pj);
                if (!sc && !sp) sS[r] += ep;                   // dadc: neg-sum
                const float w = (!sc && sp) ? 2.f : ((sc && !sp) ? 1.f : 0.f);
                sP[r] += w * p;
                sE[r] += w * ep;
                sW[r] += w;
            }
        }
#pragma unroll
        for (int r = 0; r < 4; ++r) {
            float vS = sS[r], vP = sP[r], vE = sE[r], vW = sW[r];
#pragma unroll
            for (int off = 1; off < 16; off <<= 1) {
                vS += __shfl_xor(vS, off);
                vP += __shfl_xor(vP, off);
                vE += __shfl_xor(vE, off);
                vW += __shfl_xor(vW, off);
            }
            if (rA == 0) {   // 2 contributors per row (wc=0,1): commutative => deterministic
                const int row = rbase + r;
                atomicAdd(&accS[row], vS);
                atomicAdd(&accP[row], vP);
                atomicAdd(&accE[row], vE);
                atomicAdd(&accW[row], vW);
            }
        }
    }
    __syncthreads();
    if (tid < 128) {
        float4 o = make_float4(accS[tid], accP[tid], accE[tid], accW[tid]);
        ((float4*)partials)[(size_t)(i0 + tid) * 32 + g] = o;
    }
}

// loss_i = W_i*log(S_i) - P_i + E_i/S_i ; out = sum_i loss_i / N
__global__ void k_final(const float* __restrict__ partials, float* __restrict__ out) {
    __shared__ float red[256];
    const int t = threadIdx.x;
    float local = 0.f;
    for (int i = t; i < N; i += 256) {
        const float4* p = ((const float4*)partials) + (size_t)i * 32;
        float S = 0.f, P = 0.f, E = 0.f, W = 0.f;
        for (int gg = 0; gg < 32; ++gg) {
            float4 v = p[gg];
            S += v.x; P += v.y; E += v.z; W += v.w;
        }
        local += W * logf(S) - P + E / S;
    }
    red[t] = local;
    __syncthreads();
    for (int s = 128; s > 0; s >>= 1) {
        if (t < s) red[t] += red[t + s];
        __syncthreads();
    }
    if (t == 0) out[0] = red[0] / (float)N;
}

extern "C" void kernel_launch(void* const* d_in, const int* in_sizes, int n_in,
                              void* d_out, int out_size, void* d_ws, size_t ws_size,
                              hipStream_t stream) {
    const float* X = (const float*)d_in[0];
    const int*   T = (const int*)d_in[1];
    float* out = (float*)d_out;

    char* ws = (char*)d_ws;
    __bf16* Xb     = (__bf16*)ws;
    int*    cls    = (int*)(ws + (size_t)4 * 1024 * 1024);
    float*  parts  = (float*)(ws + (size_t)4 * 1024 * 1024 + 16 * 1024);

    hipLaunchKernelGGL(k_convert, dim3((N * DK / 8) / 256), dim3(256), 0, stream, X, Xb);
    hipLaunchKernelGGL(k_cls,     dim3(1),    dim3(1024), 0, stream, T, cls);
    hipLaunchKernelGGL(k_main,    dim3(1024), dim3(256),  0, stream, Xb, cls, parts);
    hipLaunchKernelGGL(k_final,   dim3(1),    dim3(256),  0, stream, parts, out);
}

// Round 2
// 56.654 us; speedup vs baseline: 2.2325x; 2.2325x over previous
//
#include <hip/hip_runtime.h>
#include <stdint.h>

#define GLOBAL_AS __attribute__((address_space(1)))
#define LDS_AS    __attribute__((address_space(3)))

typedef __attribute__((ext_vector_type(8))) __bf16 bf16x8;
typedef __attribute__((ext_vector_type(4))) float  f32x4;

static_assert(sizeof(bf16x8) == 16, "bf16x8 must be 16B");

constexpr int N  = 4096;   // B*P rows
constexpr int DK = 512;    // feature dim

// ---------------------------------------------------------------------------
// ws layout:
//   Xb       : bf16 [4096][512]        @ 0          (4 MiB)   [dead after k_main]
//   cls      : int32[4096]             @ 4 MiB      (16 KiB)
//   partials : float4 [4096][32]       @ 4MiB+16KiB (2 MiB)  {S,P,E,W}
//   blockSums: float[256]              @ 0          (aliases dead Xb; same-stream safe)
// ---------------------------------------------------------------------------

__global__ void k_convert(const float* __restrict__ X, __bf16* __restrict__ Xb) {
    int idx = blockIdx.x * blockDim.x + threadIdx.x;   // 262144 threads, 8 elems each
    const float4* s = (const float4*)X;
    float4 a = s[2 * idx + 0];
    float4 b = s[2 * idx + 1];
    bf16x8 o;
    o[0] = (__bf16)a.x; o[1] = (__bf16)a.y; o[2] = (__bf16)a.z; o[3] = (__bf16)a.w;
    o[4] = (__bf16)b.x; o[5] = (__bf16)b.y; o[6] = (__bf16)b.z; o[7] = (__bf16)b.w;
    *(bf16x8*)(Xb + 8 * idx) = o;
}

// targets may arrive as int64 (ref uses jnp.int64) or int32 (x64 disabled).
// int64 little-endian => odd int32 words are all zero (values in [0,128)).
__global__ void k_cls(const int* __restrict__ tbuf, int* __restrict__ cls) {
    __shared__ int is64;
    int t = threadIdx.x;                 // 1024 threads, 1 block
    if (t == 0) is64 = 1;
    __syncthreads();
    if (t < 512 && tbuf[2 * t + 1] != 0) is64 = 0;
    __syncthreads();
    int idx = is64 ? (2 * t) : t;
    int v = tbuf[idx];
    cls[4 * t + 0] = v;
    cls[4 * t + 1] = v;
    cls[4 * t + 2] = v;
    cls[4 * t + 3] = v;
}

// Main fused kernel: 128x128 output tile per block, K=512 loop, bf16 MFMA,
// epilogue folds (S,P,E,W) row-accumulators. Grid = 32x32 = 1024 blocks.
__launch_bounds__(256, 3)
__global__ void k_main(const __bf16* __restrict__ Xb, const int* __restrict__ cls,
                       float* __restrict__ partials) {
    __shared__ __align__(16) __bf16 As[128 * 64];   // [row][k] bf16, row stride 128B
    __shared__ __align__(16) __bf16 Bs[128 * 64];   // [col][k] bf16 (B = X^T => rows of X)
    __shared__ float accS[128], accP[128], accE[128], accW[128];
    __shared__ int rowcls[128], colcls[128];

    const int tid  = threadIdx.x;
    const int lane = tid & 63;
    const int wid  = tid >> 6;
    const int rt = blockIdx.x & 31;
    const int g  = blockIdx.x >> 5;
    const int i0 = rt * 128;
    const int j0 = g * 128;

    if (tid < 128) {
        rowcls[tid] = cls[i0 + tid];
        colcls[tid] = cls[j0 + tid];
        accS[tid] = 0.f; accP[tid] = 0.f; accE[tid] = 0.f; accW[tid] = 0.f;
    }

    const int wr = wid >> 1;          // wave row (0..1) -> rows wr*64..+63
    const int wc = wid & 1;           // wave col (0..1) -> cols wc*64..+63

    f32x4 acc[4][4] = {};

    const char* xb   = (const char*)Xb;
    const int   srow = tid >> 3;          // 0..31 (staging row within 32-row slab)
    const int   skb  = (tid & 7) * 16;    // 0..112 (staging k-byte)
    char* AsB = (char*)As;
    char* BsB = (char*)Bs;
    const int ldsOff = wid * 1024;        // wave-uniform LDS base offset

    const int rA   = lane & 15;           // fragment row/col within 16
    const int kgrp = lane >> 4;           // 0..3

    for (int kt = 0; kt < DK / 64; ++kt) {
        const size_t kb0 = (size_t)kt * 128;   // k-tile byte offset within a row
#pragma unroll
        for (int t = 0; t < 4; ++t) {
            __builtin_amdgcn_global_load_lds(
                (const GLOBAL_AS void*)(xb + (size_t)(i0 + t * 32 + srow) * 1024 + kb0 + skb),
                (LDS_AS void*)(AsB + t * 4096 + ldsOff), 16, 0, 0);
            __builtin_amdgcn_global_load_lds(
                (const GLOBAL_AS void*)(xb + (size_t)(j0 + t * 32 + srow) * 1024 + kb0 + skb),
                (LDS_AS void*)(BsB + t * 4096 + ldsOff), 16, 0, 0);
        }
        __syncthreads();
#pragma unroll
        for (int kk = 0; kk < 2; ++kk) {
            const int koff = kk * 64 + kgrp * 16;
            bf16x8 af[4], bg[4];
#pragma unroll
            for (int m = 0; m < 4; ++m)
                af[m] = *(const bf16x8*)(AsB + (wr * 64 + m * 16 + rA) * 128 + koff);
#pragma unroll
            for (int n = 0; n < 4; ++n)
                bg[n] = *(const bf16x8*)(BsB + (wc * 64 + n * 16 + rA) * 128 + koff);
#pragma unroll
            for (int m = 0; m < 4; ++m)
#pragma unroll
                for (int n = 0; n < 4; ++n)
                    acc[m][n] = __builtin_amdgcn_mfma_f32_16x16x32_bf16(af[m], bg[n],
                                                                        acc[m][n], 0, 0, 0);
        }
        __syncthreads();
    }

    // ---- epilogue: fold acc into per-row (S, P, E, W) ----
    // C/D layout: col = lane&15, row = (lane>>4)*4 + reg  [m89-verified]
    const int pj = lane & 3;
#pragma unroll
    for (int m = 0; m < 4; ++m) {
        const int rbase = wr * 64 + m * 16 + kgrp * 4;
        int ci[4];
#pragma unroll
        for (int r = 0; r < 4; ++r) ci[r] = rowcls[rbase + r];
        float sS[4] = {0.f, 0.f, 0.f, 0.f};
        float sP[4] = {0.f, 0.f, 0.f, 0.f};
        float sE[4] = {0.f, 0.f, 0.f, 0.f};
        float sW[4] = {0.f, 0.f, 0.f, 0.f};
#pragma unroll
        for (int n = 0; n < 4; ++n) {
            const int cj = colcls[wc * 64 + n * 16 + rA];
#pragma unroll
            for (int r = 0; r < 4; ++r) {
                const float p  = acc[m][n][r];
                const float ep = __expf(p);
                const bool sc = (ci[r] == cj);
                const bool sp = (r == pj);
                if (!sc && !sp) sS[r] += ep;                   // dadc: neg-sum
                const float w = (!sc && sp) ? 2.f : ((sc && !sp) ? 1.f : 0.f);
                sP[r] += w * p;
                sE[r] += w * ep;
                sW[r] += w;
            }
        }
#pragma unroll
        for (int r = 0; r < 4; ++r) {
            float vS = sS[r], vP = sP[r], vE = sE[r], vW = sW[r];
#pragma unroll
            for (int off = 1; off < 16; off <<= 1) {
                vS += __shfl_xor(vS, off);
                vP += __shfl_xor(vP, off);
                vE += __shfl_xor(vE, off);
                vW += __shfl_xor(vW, off);
            }
            if (rA == 0) {   // 2 contributors per row (wc=0,1): commutative => deterministic
                const int row = rbase + r;
                atomicAdd(&accS[row], vS);
                atomicAdd(&accP[row], vP);
                atomicAdd(&accE[row], vE);
                atomicAdd(&accW[row], vW);
            }
        }
    }
    __syncthreads();
    if (tid < 128) {
        float4 o = make_float4(accS[tid], accP[tid], accE[tid], accW[tid]);
        ((float4*)partials)[(size_t)(i0 + tid) * 32 + g] = o;
    }
}

// Stage 1: 256 blocks x 256 threads; 16 threads per row; 16 rows per block.
// loss_i = W_i*log(S_i) - P_i + E_i/S_i ; blockSums[bid] = sum of 16 row losses.
__global__ void k_rowloss(const float* __restrict__ partials, float* __restrict__ blockSums) {
    __shared__ float red[16];
    const int tid = threadIdx.x;
    const int sub = tid & 15;            // position within row
    const int row = blockIdx.x * 16 + (tid >> 4);

    const float4* p = ((const float4*)partials) + (size_t)row * 32;
    float4 a = p[sub];
    float4 b = p[sub + 16];
    float S = a.x + b.x, P = a.y + b.y, E = a.z + b.z, W = a.w + b.w;
#pragma unroll
    for (int off = 1; off < 16; off <<= 1) {
        S += __shfl_xor(S, off);
        P += __shfl_xor(P, off);
        E += __shfl_xor(E, off);
        W += __shfl_xor(W, off);
    }
    if (sub == 0) red[tid >> 4] = W * logf(S) - P + E / S;
    __syncthreads();
    if (tid == 0) {
        float s = 0.f;
#pragma unroll
        for (int r = 0; r < 16; ++r) s += red[r];
        blockSums[blockIdx.x] = s;
    }
}

// Stage 2: one tiny block reduces 256 block sums.
__global__ void k_final2(const float* __restrict__ blockSums, float* __restrict__ out) {
    const int t = threadIdx.x;           // 64 threads (one wave)
    float v = blockSums[t] + blockSums[t + 64] + blockSums[t + 128] + blockSums[t + 192];
#pragma unroll
    for (int off = 1; off < 64; off <<= 1) v += __shfl_xor(v, off);
    if (t == 0) out[0] = v / (float)N;
}

extern "C" void kernel_launch(void* const* d_in, const int* in_sizes, int n_in,
                              void* d_out, int out_size, void* d_ws, size_t ws_size,
                              hipStream_t stream) {
    const float* X = (const float*)d_in[0];
    const int*   T = (const int*)d_in[1];
    float* out = (float*)d_out;

    char* ws = (char*)d_ws;
    __bf16* Xb     = (__bf16*)ws;
    int*    cls    = (int*)(ws + (size_t)4 * 1024 * 1024);
    float*  parts  = (float*)(ws + (size_t)4 * 1024 * 1024 + 16 * 1024);
    float*  bsums  = (float*)ws;   // aliases Xb (dead after k_main; same-stream ordering)

    hipLaunchKernelGGL(k_convert, dim3((N * DK / 8) / 256), dim3(256), 0, stream, X, Xb);
    hipLaunchKernelGGL(k_cls,     dim3(1),    dim3(1024), 0, stream, T, cls);
    hipLaunchKernelGGL(k_main,    dim3(1024), dim3(256),  0, stream, Xb, cls, parts);
    hipLaunchKernelGGL(k_rowloss, dim3(256),  dim3(256),  0, stream, parts, bsums);
    hipLaunchKernelGGL(k_final2,  dim3(1),    dim3(64),   0, stream, bsums, out);
}

// Round 3
// 56.649 us; speedup vs baseline: 2.2327x; 1.0001x over previous
//
#include <hip/hip_runtime.h>
#include <stdint.h>

#define GLOBAL_AS __attribute__((address_space(1)))
#define LDS_AS    __attribute__((address_space(3)))

typedef __attribute__((ext_vector_type(8))) __bf16 bf16x8;
typedef __attribute__((ext_vector_type(4))) float  f32x4;

static_assert(sizeof(bf16x8) == 16, "bf16x8 must be 16B");

constexpr int N  = 4096;   // B*P rows
constexpr int DK = 512;    // feature dim

// ---------------------------------------------------------------------------
// ws layout:
//   Xb       : bf16 [4096][512]        @ 0          (4 MiB)   [dead after k_main]
//   cls      : int32[4096]             @ 4 MiB      (16 KiB)
//   partials : float4 [4096][32]       @ 4MiB+16KiB (2 MiB)  {S,P,E,W}
//   blockSums: float[256]              @ 0          (aliases dead Xb; same-stream safe)
// ---------------------------------------------------------------------------

__global__ void k_convert(const float* __restrict__ X, __bf16* __restrict__ Xb) {
    int idx = blockIdx.x * blockDim.x + threadIdx.x;   // 262144 threads, 8 elems each
    const float4* s = (const float4*)X;
    float4 a = s[2 * idx + 0];
    float4 b = s[2 * idx + 1];
    bf16x8 o;
    o[0] = (__bf16)a.x; o[1] = (__bf16)a.y; o[2] = (__bf16)a.z; o[3] = (__bf16)a.w;
    o[4] = (__bf16)b.x; o[5] = (__bf16)b.y; o[6] = (__bf16)b.z; o[7] = (__bf16)b.w;
    *(bf16x8*)(Xb + 8 * idx) = o;
}

// targets may arrive as int64 (ref uses jnp.int64) or int32 (x64 disabled).
// int64 little-endian => odd int32 words are all zero (values in [0,128)).
__global__ void k_cls(const int* __restrict__ tbuf, int* __restrict__ cls) {
    __shared__ int is64;
    int t = threadIdx.x;                 // 1024 threads, 1 block
    if (t == 0) is64 = 1;
    __syncthreads();
    if (t < 512 && tbuf[2 * t + 1] != 0) is64 = 0;
    __syncthreads();
    int idx = is64 ? (2 * t) : t;
    int v = tbuf[idx];
    cls[4 * t + 0] = v;
    cls[4 * t + 1] = v;
    cls[4 * t + 2] = v;
    cls[4 * t + 3] = v;
}

// Triangular 128x128-tile GEMM (rt >= g only), 2-phase prefetch double-buffer.
// Off-diagonal tiles fold BOTH row-stats (rows i0..) and col-stats (rows j0..)
// from the same accumulator (masks/weights symmetric in (i,j)).
// Grid = 32*33/2 = 528 blocks.
__launch_bounds__(256, 2)
__global__ void k_main(const __bf16* __restrict__ Xb, const int* __restrict__ cls,
                       float* __restrict__ partials) {
    __shared__ __align__(16) __bf16 As[2][128 * 64];   // [buf][row][k], row stride 128B
    __shared__ __align__(16) __bf16 Bs[2][128 * 64];
    __shared__ float accS[128], accP[128], accE[128], accW[128];       // row stats
    __shared__ float accSc[128], accPc[128], accEc[128], accWc[128];   // col stats
    __shared__ int rowcls[128], colcls[128];

    const int tid  = threadIdx.x;
    const int lane = tid & 63;
    const int wid  = tid >> 6;

    // triangular decode: bid -> (rt, g), rt >= g
    const int bid = blockIdx.x;
    int rt = (int)((sqrtf(8.0f * (float)bid + 1.0f) - 1.0f) * 0.5f);
    while (((rt + 1) * (rt + 2)) / 2 <= bid) ++rt;
    while ((rt * (rt + 1)) / 2 > bid) --rt;
    const int g  = bid - (rt * (rt + 1)) / 2;
    const int i0 = rt * 128;
    const int j0 = g * 128;
    const bool offdiag = (rt != g);

    if (tid < 128) {
        rowcls[tid] = cls[i0 + tid];
        colcls[tid] = cls[j0 + tid];
        accS[tid] = 0.f;  accP[tid] = 0.f;  accE[tid] = 0.f;  accW[tid] = 0.f;
        accSc[tid] = 0.f; accPc[tid] = 0.f; accEc[tid] = 0.f; accWc[tid] = 0.f;
    }

    const int wr = wid >> 1;          // wave row (0..1)
    const int wc = wid & 1;           // wave col (0..1)

    f32x4 acc[4][4] = {};

    const char* xb   = (const char*)Xb;
    const int   srow = tid >> 3;          // 0..31
    const int   skb  = (tid & 7) * 16;    // 0..112
    const int ldsOff = wid * 1024;        // wave-uniform LDS base offset

    const int rA   = lane & 15;
    const int kgrp = lane >> 4;

#define STAGE(buf, kt)                                                                     \
    {                                                                                      \
        const size_t kb0 = (size_t)(kt) * 128;                                             \
        char* AsB = (char*)(&As[(buf)][0]);                                                \
        char* BsB = (char*)(&Bs[(buf)][0]);                                                \
        _Pragma("unroll")                                                                  \
        for (int t = 0; t < 4; ++t) {                                                      \
            __builtin_amdgcn_global_load_lds(                                              \
                (const GLOBAL_AS void*)(xb + (size_t)(i0 + t * 32 + srow) * 1024 + kb0 + skb), \
                (LDS_AS void*)(AsB + t * 4096 + ldsOff), 16, 0, 0);                        \
            __builtin_amdgcn_global_load_lds(                                              \
                (const GLOBAL_AS void*)(xb + (size_t)(j0 + t * 32 + srow) * 1024 + kb0 + skb), \
                (LDS_AS void*)(BsB + t * 4096 + ldsOff), 16, 0, 0);                        \
        }                                                                                  \
    }

    // prologue
    STAGE(0, 0);
    __syncthreads();                       // drains vmcnt(0): buf0 ready

    int cur = 0;
#pragma unroll
    for (int kt = 0; kt < DK / 64; ++kt) {
        if (kt < DK / 64 - 1) STAGE(cur ^ 1, kt + 1);   // prefetch overlaps compute
        const char* AsB = (const char*)(&As[cur][0]);
        const char* BsB = (const char*)(&Bs[cur][0]);
#pragma unroll
        for (int kk = 0; kk < 2; ++kk) {
            const int koff = kk * 64 + kgrp * 16;
            bf16x8 af[4], bg[4];
#pragma unroll
            for (int m = 0; m < 4; ++m)
                af[m] = *(const bf16x8*)(AsB + (wr * 64 + m * 16 + rA) * 128 + koff);
#pragma unroll
            for (int n = 0; n < 4; ++n)
                bg[n] = *(const bf16x8*)(BsB + (wc * 64 + n * 16 + rA) * 128 + koff);
#pragma unroll
            for (int m = 0; m < 4; ++m)
#pragma unroll
                for (int n = 0; n < 4; ++n)
                    acc[m][n] = __builtin_amdgcn_mfma_f32_16x16x32_bf16(af[m], bg[n],
                                                                        acc[m][n], 0, 0, 0);
        }
        if (kt < DK / 64 - 1) {
            __syncthreads();               // one barrier per iter: prefetch landed,
            cur ^= 1;                      // all waves done reading old buf
        }
    }
#undef STAGE

    // ---- epilogue: fold acc into per-row AND per-col (S, P, E, W) ----
    // C/D layout: col = lane&15, row = (lane>>4)*4 + reg  [m89-verified]
    // part(i) = i&3: row part = r (tile bases %4==0), col part = lane&3
    const int pj = lane & 3;
    int cjv[4];
#pragma unroll
    for (int n = 0; n < 4; ++n) cjv[n] = colcls[wc * 64 + n * 16 + rA];
    float cS[4] = {0.f, 0.f, 0.f, 0.f};
    float cP[4] = {0.f, 0.f, 0.f, 0.f};
    float cE[4] = {0.f, 0.f, 0.f, 0.f};
    float cW[4] = {0.f, 0.f, 0.f, 0.f};

#pragma unroll
    for (int m = 0; m < 4; ++m) {
        const int rbase = wr * 64 + m * 16 + kgrp * 4;
        int ci[4];
#pragma unroll
        for (int r = 0; r < 4; ++r) ci[r] = rowcls[rbase + r];
        float sS[4] = {0.f, 0.f, 0.f, 0.f};
        float sP[4] = {0.f, 0.f, 0.f, 0.f};
        float sE[4] = {0.f, 0.f, 0.f, 0.f};
        float sW[4] = {0.f, 0.f, 0.f, 0.f};
#pragma unroll
        for (int n = 0; n < 4; ++n) {
            const int cj = cjv[n];
#pragma unroll
            for (int r = 0; r < 4; ++r) {
                const float p  = acc[m][n][r];
                const float ep = __expf(p);
                const bool sc = (ci[r] == cj);
                const bool sp = (r == pj);
                const bool dadc = (!sc && !sp);
                if (dadc) { sS[r] += ep; cS[n] += ep; }
                const float w = (!sc && sp) ? 2.f : ((sc && !sp) ? 1.f : 0.f);
                sP[r] += w * p;  sE[r] += w * ep;  sW[r] += w;
                cP[n] += w * p;  cE[n] += w * ep;  cW[n] += w;
            }
        }
#pragma unroll
        for (int r = 0; r < 4; ++r) {
            float vS = sS[r], vP = sP[r], vE = sE[r], vW = sW[r];
#pragma unroll
            for (int off = 1; off < 16; off <<= 1) {
                vS += __shfl_xor(vS, off);
                vP += __shfl_xor(vP, off);
                vE += __shfl_xor(vE, off);
                vW += __shfl_xor(vW, off);
            }
            if (rA == 0) {   // 2 contributors (wc=0,1): exact commutative => deterministic
                const int row = rbase + r;
                atomicAdd(&accS[row], vS);
                atomicAdd(&accP[row], vP);
                atomicAdd(&accE[row], vE);
                atomicAdd(&accW[row], vW);
            }
        }
    }

    if (offdiag) {
#pragma unroll
        for (int n = 0; n < 4; ++n) {
            float vS = cS[n], vP = cP[n], vE = cE[n], vW = cW[n];
            // reduce over kgrp axis (lanes sharing lane&15): xor 16, 32
            vS += __shfl_xor(vS, 16); vS += __shfl_xor(vS, 32);
            vP += __shfl_xor(vP, 16); vP += __shfl_xor(vP, 32);
            vE += __shfl_xor(vE, 16); vE += __shfl_xor(vE, 32);
            vW += __shfl_xor(vW, 16); vW += __shfl_xor(vW, 32);
            if (kgrp == 0) {   // 2 contributors (wr=0,1): deterministic
                const int col = wc * 64 + n * 16 + rA;
                atomicAdd(&accSc[col], vS);
                atomicAdd(&accPc[col], vP);
                atomicAdd(&accEc[col], vE);
                atomicAdd(&accWc[col], vW);
            }
        }
    }

    __syncthreads();
    if (tid < 128) {
        float4 o = make_float4(accS[tid], accP[tid], accE[tid], accW[tid]);
        ((float4*)partials)[(size_t)(i0 + tid) * 32 + g] = o;
        if (offdiag) {
            float4 oc = make_float4(accSc[tid], accPc[tid], accEc[tid], accWc[tid]);
            ((float4*)partials)[(size_t)(j0 + tid) * 32 + rt] = oc;
        }
    }
}

// Stage 1: 256 blocks x 256 threads; 16 threads per row; 16 rows per block.
__global__ void k_rowloss(const float* __restrict__ partials, float* __restrict__ blockSums) {
    __shared__ float red[16];
    const int tid = threadIdx.x;
    const int sub = tid & 15;
    const int row = blockIdx.x * 16 + (tid >> 4);

    const float4* p = ((const float4*)partials) + (size_t)row * 32;
    float4 a = p[sub];
    float4 b = p[sub + 16];
    float S = a.x + b.x, P = a.y + b.y, E = a.z + b.z, W = a.w + b.w;
#pragma unroll
    for (int off = 1; off < 16; off <<= 1) {
        S += __shfl_xor(S, off);
        P += __shfl_xor(P, off);
        E += __shfl_xor(E, off);
        W += __shfl_xor(W, off);
    }
    if (sub == 0) red[tid >> 4] = W * logf(S) - P + E / S;
    __syncthreads();
    if (tid == 0) {
        float s = 0.f;
#pragma unroll
        for (int r = 0; r < 16; ++r) s += red[r];
        blockSums[blockIdx.x] = s;
    }
}

__global__ void k_final2(const float* __restrict__ blockSums, float* __restrict__ out) {
    const int t = threadIdx.x;           // 64 threads
    float v = blockSums[t] + blockSums[t + 64] + blockSums[t + 128] + blockSums[t + 192];
#pragma unroll
    for (int off = 1; off < 64; off <<= 1) v += __shfl_xor(v, off);
    if (t == 0) out[0] = v / (float)N;
}

extern "C" void kernel_launch(void* const* d_in, const int* in_sizes, int n_in,
                              void* d_out, int out_size, void* d_ws, size_t ws_size,
                              hipStream_t stream) {
    const float* X = (const float*)d_in[0];
    const int*   T = (const int*)d_in[1];
    float* out = (float*)d_out;

    char* ws = (char*)d_ws;
    __bf16* Xb     = (__bf16*)ws;
    int*    cls    = (int*)(ws + (size_t)4 * 1024 * 1024);
    float*  parts  = (float*)(ws + (size_t)4 * 1024 * 1024 + 16 * 1024);
    float*  bsums  = (float*)ws;   // aliases Xb (dead after k_main; same-stream ordering)

    hipLaunchKernelGGL(k_convert, dim3((N * DK / 8) / 256), dim3(256), 0, stream, X, Xb);
    hipLaunchKernelGGL(k_cls,     dim3(1),   dim3(1024), 0, stream, T, cls);
    hipLaunchKernelGGL(k_main,    dim3(528), dim3(256),  0, stream, Xb, cls, parts);
    hipLaunchKernelGGL(k_rowloss, dim3(256), dim3(256),  0, stream, parts, bsums);
    hipLaunchKernelGGL(k_final2,  dim3(1),   dim3(64),   0, stream, bsums, out);
}